// Round 3
// baseline (129.119 us; speedup 1.0000x reference)
//
#include <hip/hip_runtime.h>
#include <hip/hip_bf16.h>

// u_mul_v: out[e, :] = h[src[e], :] * h[dst[e], :]
// h: [10000, 128] f32, src/dst: [640000] int32, out: [640000, 128] f32.
//
// Memory-bound. HBM floor ~48-54 us (327.7 MB store stream at the
// measured 7 TB/s fill rate + ~10 MB reads; h gathers served by L2/L3).
//
// Round-3 structure:
//  - 32 lanes per edge, one float4 per lane: every VMEM instr is a fully
//    coalesced 512 B-per-32-lane access.
//  - U=8 clustered phases: 16 idx loads -> 16 gathers -> 8 stores per
//    thread; 16 independent gather chains in flight.
//  - Nontemporal idx loads (streamed once, keep L2 for h) and
//    nontemporal stores (keep the 327 MB write stream from evicting h).
//  - No bounds checks in the hot kernel: exact-division main grid +
//    separate tail kernel (0 blocks for this shape).

using f32x4 = __attribute__((ext_vector_type(4))) float;

constexpr int U = 8;
constexpr int BLOCK = 256;

__global__ __launch_bounds__(BLOCK) void u_mul_v_main(
    const f32x4* __restrict__ h4,
    const int* __restrict__ src,
    const int* __restrict__ dst,
    f32x4* __restrict__ out4)
{
    const int T = gridDim.x * BLOCK;                  // stride between u's
    const int tid = blockIdx.x * BLOCK + threadIdx.x;

    // Phase 1: all index loads (nontemporal; same addr across 32 lanes)
    int es[U], ed[U];
#pragma unroll
    for (int u = 0; u < U; u++) {
        int e = (tid + u * T) >> 5;
        es[u] = __builtin_nontemporal_load(&src[e]);
        ed[u] = __builtin_nontemporal_load(&dst[e]);
    }

    // Phase 2: all gathers (normal caching; h should live in L2)
    f32x4 a[U], b[U];
#pragma unroll
    for (int u = 0; u < U; u++) {
        int c = (tid + u * T) & 31;
        a[u] = h4[es[u] * 32 + c];   // 32-bit offsets: max 10000*32
        b[u] = h4[ed[u] * 32 + c];
    }

    // Phase 3: multiply + nontemporal streaming stores
#pragma unroll
    for (int u = 0; u < U; u++) {
        __builtin_nontemporal_store(a[u] * b[u], &out4[tid + u * T]);
    }
}

__global__ __launch_bounds__(BLOCK) void u_mul_v_tail(
    const f32x4* __restrict__ h4,
    const int* __restrict__ src,
    const int* __restrict__ dst,
    f32x4* __restrict__ out4,
    int base, int n_f4)
{
    int i = base + blockIdx.x * BLOCK + threadIdx.x;
    if (i < n_f4) {
        int e = i >> 5, c = i & 31;
        f32x4 a = h4[src[e] * 32 + c];
        f32x4 b = h4[dst[e] * 32 + c];
        out4[i] = a * b;
    }
}

extern "C" void kernel_launch(void* const* d_in, const int* in_sizes, int n_in,
                              void* d_out, int out_size, void* d_ws, size_t ws_size,
                              hipStream_t stream) {
    const f32x4* h4 = (const f32x4*)d_in[0];
    const int* src  = (const int*)d_in[1];
    const int* dst  = (const int*)d_in[2];
    f32x4* out4     = (f32x4*)d_out;

    int n_edges = in_sizes[1];          // 640000
    int n_f4 = n_edges * 32;            // 20,480,000 float4 elements

    int grid_main = n_f4 / (BLOCK * U); // 10000 (exact for this shape)
    int n_main = grid_main * BLOCK * U;

    if (grid_main > 0)
        u_mul_v_main<<<grid_main, BLOCK, 0, stream>>>(h4, src, dst, out4);

    int n_tail = n_f4 - n_main;         // 0 for this shape
    if (n_tail > 0) {
        int grid_tail = (n_tail + BLOCK - 1) / BLOCK;
        u_mul_v_tail<<<grid_tail, BLOCK, 0, stream>>>(h4, src, dst, out4,
                                                      n_main, n_f4);
    }
}

// Round 4
// 61.701 us; speedup vs baseline: 2.0927x; 2.0927x over previous
//
#include <hip/hip_runtime.h>
#include <hip/hip_bf16.h>

// u_mul_v: out[e, :] = h[src[e], :] * h[dst[e], :]
// h: [10000, 128] f32, src/dst: [640000] int32, out: [640000, 128] f32.
//
// Round-4 theory: round-3 profile showed FETCH_SIZE=126 MB (ideal ~10 MB)
// -> h (5.12 MB) is thrashing the 4 MiB per-XCD L2s (random gathers make
// every XCD want all of h) and the 327 MB write stream flushes L3.
//
// Fix: COLUMN-SPLIT h across XCD groups. blockIdx%8 ~ XCD id (CDNA4
// round-robin dispatch heuristic):
//   XCDs 0-3 process feature cols [0,64), XCDs 4-7 cols [64,128).
// Per-XCD h working set = 2.56 MB < 4 MiB L2 -> h stays L2-resident.
// If the %8 mapping assumption fails we only lose the residency benefit.
//
// Also: U=8 independent gather chains with sched_barrier(0)-pinned phases
// (round 3's compiler sank the gathers: VGPR_Count=32 => ~4 in flight),
// normal cached idx loads (nt idx loads regressed), nontemporal stores.

using f32x4 = __attribute__((ext_vector_type(4))) float;

constexpr int U = 8;
constexpr int BLOCK = 256;

__global__ __launch_bounds__(BLOCK) void u_mul_v_split(
    const f32x4* __restrict__ h4,
    const int* __restrict__ src,
    const int* __restrict__ dst,
    f32x4* __restrict__ out4,
    int n_half,   // E * 16 f4-chunks per column-half
    int T)        // per-half thread count = G_half * BLOCK
{
    const int b = blockIdx.x;
    const int r = b & 7;                      // ~ XCD id
    const int half = r >> 2;                  // 0: cols [0,16) f4, 1: [16,32)
    const int bh = ((b >> 3) << 2) + (r & 3); // within-half block index
    const int tid = bh * BLOCK + threadIdx.x;

    // Phase 1: index loads (cached; neighboring waves share lines)
    int j[U], es[U], ed[U];
    bool ok[U];
#pragma unroll
    for (int u = 0; u < U; u++) {
        j[u] = tid + u * T;
        ok[u] = j[u] < n_half;
        int e = ok[u] ? (j[u] >> 4) : 0;
        es[u] = src[e];
        ed[u] = dst[e];
    }
    __builtin_amdgcn_sched_barrier(0);

    // Phase 2: all 2*U gathers issued back-to-back (h half is L2-resident)
    f32x4 a[U], bb[U];
#pragma unroll
    for (int u = 0; u < U; u++) {
        int c = (j[u] & 15) + (half << 4);
        a[u]  = h4[es[u] * 32 + c];
        bb[u] = h4[ed[u] * 32 + c];
    }
    __builtin_amdgcn_sched_barrier(0);

    // Phase 3: multiply + nontemporal streaming stores
#pragma unroll
    for (int u = 0; u < U; u++) {
        int c = (j[u] & 15) + (half << 4);
        int o = (j[u] >> 4) * 32 + c;
        if (ok[u])
            __builtin_nontemporal_store(a[u] * bb[u], &out4[o]);
    }
}

extern "C" void kernel_launch(void* const* d_in, const int* in_sizes, int n_in,
                              void* d_out, int out_size, void* d_ws, size_t ws_size,
                              hipStream_t stream) {
    const f32x4* h4 = (const f32x4*)d_in[0];
    const int* src  = (const int*)d_in[1];
    const int* dst  = (const int*)d_in[2];
    f32x4* out4     = (f32x4*)d_out;

    int n_edges = in_sizes[1];            // 640000
    int n_half = n_edges * 16;            // 10,240,000 f4-chunks per half

    int g_half = (n_half + BLOCK * U - 1) / (BLOCK * U);  // 5000
    g_half = (g_half + 3) & ~3;           // multiple of 4 for clean XCD split
    int T = g_half * BLOCK;               // 1,280,000

    int grid = 2 * g_half;                // 10000 blocks
    u_mul_v_split<<<grid, BLOCK, 0, stream>>>(h4, src, dst, out4, n_half, T);
}

// Round 5
// 59.035 us; speedup vs baseline: 2.1872x; 1.0452x over previous
//
#include <hip/hip_runtime.h>

// u_mul_v: out[e, :] = h[src[e], :] * h[dst[e], :]
// h: [10000, 128] f32, src/dst: [640000] int32, out: [640000, 128] f32.
//
// Winning structure (round 4, 61.7 us): 2-way feature-column split across
// XCD groups (blockIdx%8 ~ XCD; XCDs 0-3 -> cols [0,64), 4-7 -> [64,128)),
// so each XCD's L2 holds a 2.56 MB half of h -> no h thrash (round-3
// profile: FETCH 126 MB -> fixed). U=8 chains, sched_barrier-pinned
// phases, nontemporal stores, cached idx loads.
//
// Round-5 delta: each thread owns 8 CONSECUTIVE edges (u-major mapping
// within each 16-lane group) so the 16 scalar index loads become 4 int4
// vector loads (VMEM/thread 40 -> 28); bounds checks removed (exact
// division: 640000 edges % 128 edges/block == 0; fallback kernel guards
// the general case).

using f32x4 = __attribute__((ext_vector_type(4))) float;
using i32x4 = __attribute__((ext_vector_type(4))) int;

constexpr int U = 8;
constexpr int BLOCK = 256;
constexpr int EDGES_PER_BLOCK = BLOCK * U / 16;   // 128

__global__ __launch_bounds__(BLOCK) void u_mul_v_split(
    const f32x4* __restrict__ h4,
    const int* __restrict__ src,
    const int* __restrict__ dst,
    f32x4* __restrict__ out4,
    int g_half)   // blocks per column-half
{
    const int b = blockIdx.x;
    const int r = b & 7;                      // ~ XCD id
    const int half = r >> 2;                  // 0: f4-cols [0,16), 1: [16,32)
    const int bh = ((b >> 3) << 2) + (r & 3); // within-half block index
    const int t = threadIdx.x;

    const int e0 = bh * EDGES_PER_BLOCK + (t >> 4) * U;  // first of 8 edges
    const int c  = (t & 15) + (half << 4);               // f4 column

    // Phase 1: vectorized index loads (16 lanes broadcast each line)
    i32x4 s_lo = *(const i32x4*)&src[e0];
    i32x4 s_hi = *(const i32x4*)&src[e0 + 4];
    i32x4 d_lo = *(const i32x4*)&dst[e0];
    i32x4 d_hi = *(const i32x4*)&dst[e0 + 4];
    __builtin_amdgcn_sched_barrier(0);

    // Phase 2: all 16 gathers back-to-back (h half is L2-resident)
    f32x4 a[U], bb[U];
#pragma unroll
    for (int u = 0; u < U; u++) {
        int es = (u < 4) ? s_lo[u & 3] : s_hi[u & 3];
        int ed = (u < 4) ? d_lo[u & 3] : d_hi[u & 3];
        a[u]  = h4[es * 32 + c];
        bb[u] = h4[ed * 32 + c];
    }
    __builtin_amdgcn_sched_barrier(0);

    // Phase 3: multiply + nontemporal streaming stores (256 B segments)
#pragma unroll
    for (int u = 0; u < U; u++) {
        __builtin_nontemporal_store(a[u] * bb[u], &out4[(e0 + u) * 32 + c]);
    }
}

// Generic fallback (any shape), round-1 style.
__global__ __launch_bounds__(BLOCK) void u_mul_v_generic(
    const f32x4* __restrict__ h4,
    const int* __restrict__ src,
    const int* __restrict__ dst,
    f32x4* __restrict__ out4,
    int n_f4)
{
    int stride = gridDim.x * BLOCK;
    for (int i = blockIdx.x * BLOCK + threadIdx.x; i < n_f4; i += stride) {
        int e = i >> 5, c = i & 31;
        f32x4 a = h4[src[e] * 32 + c];
        f32x4 b = h4[dst[e] * 32 + c];
        out4[i] = a * b;
    }
}

extern "C" void kernel_launch(void* const* d_in, const int* in_sizes, int n_in,
                              void* d_out, int out_size, void* d_ws, size_t ws_size,
                              hipStream_t stream) {
    const f32x4* h4 = (const f32x4*)d_in[0];
    const int* src  = (const int*)d_in[1];
    const int* dst  = (const int*)d_in[2];
    f32x4* out4     = (f32x4*)d_out;

    int n_edges = in_sizes[1];            // 640000
    int n_f4 = n_edges * 32;

    if (n_edges % EDGES_PER_BLOCK == 0) {
        int g_half = n_edges / EDGES_PER_BLOCK;   // 5000
        int grid = 2 * g_half;                    // 10000 blocks
        u_mul_v_split<<<grid, BLOCK, 0, stream>>>(h4, src, dst, out4, g_half);
    } else {
        u_mul_v_generic<<<2048, BLOCK, 0, stream>>>(h4, src, dst, out4, n_f4);
    }
}